// Round 11
// baseline (59.170 us; speedup 1.0000x reference)
//
#include <hip/hip_runtime.h>

#define HID 32
#define LAT 8
#define BSH 8                 // 256 nodes per bucket
#define BUCK 256
#define CB 512                // consumer threads per block
#define PB 512                // threads per place/hist block
#define PEV 16                // edges per thread
#define PCHUNK (PB * PEV)     // 8192 edges per block
#define SCAN_BS 256
#define SCAN_VPT 8
#define SCAN_CHUNK (SCAN_BS * SCAN_VPT)  // 2048

__device__ __forceinline__ double atomAddF64(double* p, double v) {
    return unsafeAtomicAdd(p, v);
}

__global__ void zero_kernel(unsigned* __restrict__ p, int n) {
    int i = blockIdx.x * blockDim.x + threadIdx.x;
    if (i < n) p[i] = 0;
}

// ---------- fast path: deterministic bucket sort by dst>>8, zero global atomics

// A: per-block LDS histogram -> histMat[bin][block] (bin-major for the scan)
__global__ __launch_bounds__(PB)
void hist_kernel(const unsigned* __restrict__ dst, int E, int NB, int HBn,
                 unsigned* __restrict__ histMat) {
    __shared__ unsigned cnt[512];
    int tid = threadIdx.x;
    cnt[tid] = 0;
    __syncthreads();
    int E4 = E >> 2;
    int base4 = blockIdx.x * (PCHUNK / 4);
    #pragma unroll
    for (int k = 0; k < PEV / 4; k++) {
        int i4 = base4 + k * PB + tid;
        if (i4 < E4) {
            uint4 d = ((const uint4*)dst)[i4];
            atomicAdd(&cnt[d.x >> BSH], 1u);
            atomicAdd(&cnt[d.y >> BSH], 1u);
            atomicAdd(&cnt[d.z >> BSH], 1u);
            atomicAdd(&cnt[d.w >> BSH], 1u);
        }
    }
    __syncthreads();
    if (tid < HBn) histMat[(size_t)tid * NB + blockIdx.x] = cnt[tid];
}

// B1: per-block sums for exclusive scan
__global__ void scan_reduce(const unsigned* __restrict__ in, int M,
                            unsigned* __restrict__ partials) {
    int base = blockIdx.x * SCAN_CHUNK + threadIdx.x * SCAN_VPT;
    unsigned s = 0;
    #pragma unroll
    for (int k = 0; k < SCAN_VPT; k++) { int i = base + k; if (i < M) s += in[i]; }
    __shared__ unsigned red[SCAN_BS];
    red[threadIdx.x] = s; __syncthreads();
    for (int off = SCAN_BS / 2; off > 0; off >>= 1) {
        if (threadIdx.x < off) red[threadIdx.x] += red[threadIdx.x + off];
        __syncthreads();
    }
    if (threadIdx.x == 0) partials[blockIdx.x] = red[0];
}

// B2: single-block exclusive scan of partials (SB <= SCAN_BS)
__global__ void scan_partials(unsigned* __restrict__ partials, int SB) {
    __shared__ unsigned lds[SCAN_BS];
    unsigned v = (threadIdx.x < SB) ? partials[threadIdx.x] : 0;
    lds[threadIdx.x] = v; __syncthreads();
    for (int off = 1; off < SCAN_BS; off <<= 1) {
        unsigned t = (threadIdx.x >= off) ? lds[threadIdx.x - off] : 0;
        __syncthreads();
        lds[threadIdx.x] += t;
        __syncthreads();
    }
    if (threadIdx.x < SB) partials[threadIdx.x] = lds[threadIdx.x] - v;
}

// B3: per-block exclusive scan + partial offset, in place
__global__ void scan_apply(unsigned* __restrict__ data, int M,
                           const unsigned* __restrict__ partials) {
    int base = blockIdx.x * SCAN_CHUNK + threadIdx.x * SCAN_VPT;
    unsigned vals[SCAN_VPT]; unsigned s = 0;
    #pragma unroll
    for (int k = 0; k < SCAN_VPT; k++) {
        int i = base + k; vals[k] = (i < M) ? data[i] : 0; s += vals[k];
    }
    __shared__ unsigned lds[SCAN_BS];
    lds[threadIdx.x] = s; __syncthreads();
    for (int off = 1; off < SCAN_BS; off <<= 1) {
        unsigned t = (threadIdx.x >= off) ? lds[threadIdx.x - off] : 0;
        __syncthreads();
        lds[threadIdx.x] += t;
        __syncthreads();
    }
    unsigned excl = lds[threadIdx.x] - s + partials[blockIdx.x];
    #pragma unroll
    for (int k = 0; k < SCAN_VPT; k++) {
        int i = base + k;
        if (i < M) { unsigned v = vals[k]; data[i] = excl; excl += v; }
    }
}

// C: place with deterministic bases from the scanned matrix. Packed csr.
__global__ __launch_bounds__(PB)
void place4_kernel(const unsigned* __restrict__ src, const unsigned* __restrict__ dst,
                   int E, int NB, int HBn,
                   const unsigned* __restrict__ S, unsigned* __restrict__ csr) {
    __shared__ unsigned cnt[512];
    __shared__ unsigned gbase[512];
    uint4 dv[PEV / 4];
    unsigned rank[PEV];
    int tid = threadIdx.x;

    cnt[tid] = 0;
    __syncthreads();

    int E4 = E >> 2;
    int base4 = blockIdx.x * (PCHUNK / 4);
    #pragma unroll
    for (int k = 0; k < PEV / 4; k++) {
        int i4 = base4 + k * PB + tid;
        if (i4 < E4) {
            dv[k] = ((const uint4*)dst)[i4];
            rank[4 * k + 0] = atomicAdd(&cnt[dv[k].x >> BSH], 1u);
            rank[4 * k + 1] = atomicAdd(&cnt[dv[k].y >> BSH], 1u);
            rank[4 * k + 2] = atomicAdd(&cnt[dv[k].z >> BSH], 1u);
            rank[4 * k + 3] = atomicAdd(&cnt[dv[k].w >> BSH], 1u);
        }
    }
    __syncthreads();

    if (tid < HBn) gbase[tid] = S[(size_t)tid * NB + blockIdx.x];
    __syncthreads();

    #pragma unroll
    for (int k = 0; k < PEV / 4; k++) {
        int i4 = base4 + k * PB + tid;
        if (i4 < E4) {
            uint4 sv = ((const uint4*)src)[i4];
            unsigned d, bin;
            d = dv[k].x; bin = d >> BSH;
            csr[gbase[bin] + rank[4 * k + 0]] = ((d & (BUCK - 1u)) << 17) | sv.x;
            d = dv[k].y; bin = d >> BSH;
            csr[gbase[bin] + rank[4 * k + 1]] = ((d & (BUCK - 1u)) << 17) | sv.y;
            d = dv[k].z; bin = d >> BSH;
            csr[gbase[bin] + rank[4 * k + 2]] = ((d & (BUCK - 1u)) << 17) | sv.z;
            d = dv[k].w; bin = d >> BSH;
            csr[gbase[bin] + rank[4 * k + 3]] = ((d & (BUCK - 1u)) << 17) | sv.w;
        }
    }
}

// Per-bucket degree -> dinv,y32; fused graph-bounds computation.
__global__ __launch_bounds__(CB)
void bdeg_kernel(const unsigned* __restrict__ S, int NB, int HBn,
                 const unsigned* __restrict__ csr, int E, int N, int G,
                 const float* __restrict__ x, const int* __restrict__ batch,
                 float* __restrict__ dinv, float* __restrict__ y32,
                 int* __restrict__ startArr) {
    int b = blockIdx.x;
    __shared__ unsigned cnt[BUCK];
    if (threadIdx.x < BUCK) cnt[threadIdx.x] = 0;
    __syncthreads();
    unsigned s0 = S[(size_t)b * NB];
    unsigned s1 = (b < HBn - 1) ? S[(size_t)(b + 1) * NB] : (unsigned)E;
    // alignment head
    unsigned ah = (4u - (s0 & 3u)) & 3u;
    if (ah > s1 - s0) ah = s1 - s0;
    if (threadIdx.x < ah) atomicAdd(&cnt[csr[s0 + threadIdx.x] >> 17], 1u);
    unsigned a0 = s0 + ah;
    unsigned n4 = (s1 - a0) >> 2;
    const uint4* seg4 = (const uint4*)(csr + a0);
    for (unsigned i = threadIdx.x; i < n4; i += CB) {
        uint4 v = seg4[i];
        atomicAdd(&cnt[v.x >> 17], 1u);
        atomicAdd(&cnt[v.y >> 17], 1u);
        atomicAdd(&cnt[v.z >> 17], 1u);
        atomicAdd(&cnt[v.w >> 17], 1u);
    }
    unsigned t = a0 + (n4 << 2) + threadIdx.x;
    if (t < s1) atomicAdd(&cnt[csr[t] >> 17], 1u);
    __syncthreads();
    if (threadIdx.x < BUCK) {
        int node = (b << BSH) + threadIdx.x;
        if (node < N) {
            double dv = 1.0 / sqrt((double)(cnt[threadIdx.x] + 1));   // +1 self-loop
            dinv[node] = (float)dv;
            y32[node] = (float)((double)x[node] * dv);
            int b1 = batch[node];
            if (node == 0) { for (int g = 0; g <= b1; g++) startArr[g] = 0; }
            else { int bp = batch[node - 1]; for (int g = bp + 1; g <= b1; g++) startArr[g] = node; }
            if (node == N - 1) { for (int g = b1 + 1; g <= G; g++) startArr[g] = N; }
        }
    }
}

// Per-bucket message sum; acc[node] = dinv*(y_self + sum).
__global__ __launch_bounds__(CB)
void bsum_kernel(const unsigned* __restrict__ S, int NB, int HBn,
                 const unsigned* __restrict__ csr, int E, int N,
                 const float* __restrict__ dinv, const float* __restrict__ y32,
                 double* __restrict__ acc) {
    int b = blockIdx.x;
    __shared__ double accs[BUCK];
    if (threadIdx.x < BUCK) accs[threadIdx.x] = 0.0;
    __syncthreads();
    unsigned s0 = S[(size_t)b * NB];
    unsigned s1 = (b < HBn - 1) ? S[(size_t)(b + 1) * NB] : (unsigned)E;
    unsigned ah = (4u - (s0 & 3u)) & 3u;
    if (ah > s1 - s0) ah = s1 - s0;
    if (threadIdx.x < ah) {
        unsigned v = csr[s0 + threadIdx.x];
        atomicAdd(&accs[v >> 17], (double)y32[v & 0x1FFFFu]);
    }
    unsigned a0 = s0 + ah;
    unsigned n4 = (s1 - a0) >> 2;
    const uint4* seg4 = (const uint4*)(csr + a0);
    for (unsigned i = threadIdx.x; i < n4; i += CB) {
        uint4 v = seg4[i];
        float ya = y32[v.x & 0x1FFFFu];
        float yb = y32[v.y & 0x1FFFFu];
        float yc = y32[v.z & 0x1FFFFu];
        float yd = y32[v.w & 0x1FFFFu];
        atomicAdd(&accs[v.x >> 17], (double)ya);
        atomicAdd(&accs[v.y >> 17], (double)yb);
        atomicAdd(&accs[v.z >> 17], (double)yc);
        atomicAdd(&accs[v.w >> 17], (double)yd);
    }
    unsigned t = a0 + (n4 << 2) + threadIdx.x;
    if (t < s1) {
        unsigned v = csr[t];
        atomicAdd(&accs[v >> 17], (double)y32[v & 0x1FFFFu]);
    }
    __syncthreads();
    if (threadIdx.x < BUCK) {
        int node = (b << BSH) + threadIdx.x;
        if (node < N)
            acc[node] = (double)dinv[node] * ((double)y32[node] + accs[threadIdx.x]);
    }
}

// ---------- fallback path (R2 algorithm, small ws or odd shapes) ----------

__global__ void deg_kernel(const int* __restrict__ dst, int E, int* __restrict__ deg) {
    int e = blockIdx.x * blockDim.x + threadIdx.x;
    if (e < E) atomicAdd(&deg[dst[e]], 1);
}
__global__ void y_kernel(const float* __restrict__ x, const int* __restrict__ deg,
                         int N, double* __restrict__ y, double* __restrict__ acc) {
    int i = blockIdx.x * blockDim.x + threadIdx.x;
    if (i < N) {
        double dv = 1.0 / sqrt((double)(deg[i] + 1));
        double yi = (double)x[i] * dv;
        y[i] = yi; acc[i] = yi;
    }
}
__global__ void scatter_kernel(const int* __restrict__ ei, int E,
                               const double* __restrict__ y, double* __restrict__ acc) {
    int e = blockIdx.x * blockDim.x + threadIdx.x;
    if (e < E) atomAddF64(&acc[ei[E + e]], y[ei[e]]);
}
__global__ void finalize_kernel(const int* __restrict__ deg, int N, double* __restrict__ acc) {
    int i = blockIdx.x * blockDim.x + threadIdx.x;
    if (i < N) acc[i] *= 1.0 / sqrt((double)(deg[i] + 1));
}
__global__ void bounds_kernel(const int* __restrict__ batch, int N, int G,
                              int* __restrict__ start) {
    int i = blockIdx.x * blockDim.x + threadIdx.x;
    if (i >= N) return;
    int b1 = batch[i];
    if (i == 0) { for (int g = 0; g <= b1; g++) start[g] = 0; }
    else { int b0 = batch[i - 1]; for (int g = b0 + 1; g <= b1; g++) start[g] = i; }
    if (i == N - 1) { for (int g = b1 + 1; g <= G; g++) start[g] = N; }
}

// ---------- shared tail: fused pool + heads + decoder, one wave per graph ----

__global__ __launch_bounds__(64)
void graph_kernel(const int* __restrict__ start, const double* __restrict__ acc,
                  const float* __restrict__ W, const float* __restrict__ b,
                  const float* __restrict__ w_mu, const float* __restrict__ b_mu,
                  const float* __restrict__ w_lv, const float* __restrict__ b_lv,
                  const float* __restrict__ w_dec, const float* __restrict__ b_dec,
                  const float* __restrict__ eps,
                  float* __restrict__ out, int G) {
    int g = blockIdx.x, lane = threadIdx.x;
    int s0 = start[g], s1 = start[g + 1];

    double hacc[HID];
    #pragma unroll
    for (int j = 0; j < HID; j++) hacc[j] = 0.0;

    for (int i = s0 + lane; i < s1; i += 64) {
        double s = acc[i];
        #pragma unroll
        for (int j = 0; j < HID; j++) {
            double h = (double)W[j] * s + (double)b[j];
            hacc[j] += (h > 0.0) ? h : 0.0;
        }
    }

    #pragma unroll
    for (int m = 1; m < 64; m <<= 1) {
        #pragma unroll
        for (int j = 0; j < HID; j++) hacc[j] += __shfl_xor(hacc[j], m, 64);
    }

    int c = s1 - s0;
    double denom = (c > 0) ? (double)c : 1.0;
    #pragma unroll
    for (int j = 0; j < HID; j++) hacc[j] /= denom;

    double mv = 0.0;
    if (lane < 16) {
        int l = lane & (LAT - 1);
        const float* wm = (lane < LAT) ? w_mu : w_lv;
        const float* bm = (lane < LAT) ? b_mu : b_lv;
        double a = (double)bm[l];
        #pragma unroll
        for (int j = 0; j < HID; j++) a += hacc[j] * (double)wm[j * LAT + l];
        mv = a;
        if (lane < LAT) out[(size_t)G * 100 + (size_t)g * LAT + l] = (float)a;
        else            out[(size_t)G * 100 + (size_t)G * LAT + (size_t)g * LAT + l] = (float)a;
    }

    double z[LAT];
    #pragma unroll
    for (int l = 0; l < LAT; l++) {
        double mu_l = __shfl(mv, l, 64);
        double lv_l = __shfl(mv, l + LAT, 64);
        z[l] = mu_l + (double)eps[(size_t)g * LAT + l] * exp(0.5 * lv_l);
    }

    for (int t = lane; t < 100; t += 64) {
        double lg = (double)b_dec[t];
        #pragma unroll
        for (int l = 0; l < LAT; l++) lg += z[l] * (double)w_dec[l * 100 + t];
        out[(size_t)g * 100 + t] = (lg > 0.0) ? 1.0f : 0.0f;
    }
}

extern "C" void kernel_launch(void* const* d_in, const int* in_sizes, int n_in,
                              void* d_out, int out_size, void* d_ws, size_t ws_size,
                              hipStream_t stream) {
    const float* x     = (const float*)d_in[0];
    const int*   ei    = (const int*)d_in[1];
    const int*   batch = (const int*)d_in[2];
    const float* W     = (const float*)d_in[3];
    const float* b     = (const float*)d_in[4];
    const float* w_mu  = (const float*)d_in[5];
    const float* b_mu  = (const float*)d_in[6];
    const float* w_lv  = (const float*)d_in[7];
    const float* b_lv  = (const float*)d_in[8];
    const float* w_dec = (const float*)d_in[9];
    const float* b_dec = (const float*)d_in[10];
    const float* eps   = (const float*)d_in[11];

    int N = in_sizes[0];
    int E = in_sizes[1] / 2;
    int G = in_sizes[11] / LAT;
    float* out = (float*)d_out;

    int HBn = (N + BUCK - 1) >> BSH;          // buckets (<=512 for N<=131072)
    int NB  = (E + PCHUNK - 1) / PCHUNK;      // hist/place blocks
    long Ml = (long)HBn * NB;
    int M = (int)Ml;
    int SB = (int)((Ml + SCAN_CHUNK - 1) / SCAN_CHUNK);

    char* ws = (char*)d_ws;
    const int bs = 256;

    // fast-path ws layout
    size_t off = 0;
    double*   acc   = (double*)(ws + off);   off += (size_t)N * 8;
    unsigned* csr   = (unsigned*)(ws + off); off += (size_t)E * 4;     // packed
    unsigned* hmat  = (unsigned*)(ws + off); off += (size_t)M * 4;
    unsigned* parts = (unsigned*)(ws + off); off += (size_t)SCAN_BS * 4;
    float*    dinv  = (float*)(ws + off);    off += (size_t)N * 4;
    float*    y32   = (float*)(ws + off);    off += (size_t)N * 4;
    int*      start = (int*)(ws + off);      off += (size_t)(G + 1) * 4;
    size_t need = off;

    bool fast = (N <= 131072) && (HBn <= 512) && (SB <= SCAN_BS)
                && (ws_size >= need) && (E % 4 == 0);

    if (fast) {
        hist_kernel<<<NB, PB, 0, stream>>>((const unsigned*)(ei + E), E, NB, HBn, hmat);
        scan_reduce<<<SB, SCAN_BS, 0, stream>>>(hmat, M, parts);
        scan_partials<<<1, SCAN_BS, 0, stream>>>(parts, SB);
        scan_apply<<<SB, SCAN_BS, 0, stream>>>(hmat, M, parts);
        place4_kernel<<<NB, PB, 0, stream>>>((const unsigned*)ei, (const unsigned*)(ei + E),
                                             E, NB, HBn, hmat, csr);
        bdeg_kernel<<<HBn, CB, 0, stream>>>(hmat, NB, HBn, csr, E, N, G, x, batch,
                                            dinv, y32, start);
        bsum_kernel<<<HBn, CB, 0, stream>>>(hmat, NB, HBn, csr, E, N, dinv, y32, acc);
    } else {
        size_t foff = 0;
        double* facc = (double*)(ws + foff); foff += (size_t)N * 8;
        double* fy   = (double*)(ws + foff); foff += (size_t)N * 8;
        int*    fdeg = (int*)(ws + foff);    foff += (size_t)N * 4;
        int*    fst  = (int*)(ws + foff);    foff += (size_t)(G + 1) * 4;
        acc = facc; start = fst;
        zero_kernel<<<(N + bs - 1) / bs, bs, 0, stream>>>((unsigned*)fdeg, N);
        deg_kernel<<<(E + bs - 1) / bs, bs, 0, stream>>>(ei + E, E, fdeg);
        y_kernel<<<(N + bs - 1) / bs, bs, 0, stream>>>(x, fdeg, N, fy, facc);
        scatter_kernel<<<(E + bs - 1) / bs, bs, 0, stream>>>(ei, E, fy, facc);
        finalize_kernel<<<(N + bs - 1) / bs, bs, 0, stream>>>(fdeg, N, facc);
        bounds_kernel<<<(N + bs - 1) / bs, bs, 0, stream>>>(batch, N, G, start);
    }

    graph_kernel<<<G, 64, 0, stream>>>(start, acc, W, b, w_mu, b_mu,
                                       w_lv, b_lv, w_dec, b_dec, eps, out, G);
}